// Round 1
// baseline (694.486 us; speedup 1.0000x reference)
//
#include <hip/hip_runtime.h>
#include <math.h>

// Problem constants (fixed by reference setup_inputs)
#define B_ROWS 4096
#define D_DIM  1024
static constexpr float TEMP = 0.2f;
static constexpr float EPSN = 1e-12f;

// ws layout (floats):
//   w[0] = pos_sum accumulator
//   w[1] = neg_sum accumulator
//   w[2 .. 2+B)        = inv_norm of emb_i rows
//   w[2+B .. 2+2B)     = inv_norm of emb_j rows

__global__ void init_acc_kernel(float* __restrict__ w) {
    w[0] = 0.0f;
    w[1] = 0.0f;
}

// One block (256 threads) per row; rows [0,B) -> emb_i, [B,2B) -> emb_j.
__global__ __launch_bounds__(256) void row_invnorm_kernel(
        const float* __restrict__ emb_i,
        const float* __restrict__ emb_j,
        float* __restrict__ w) {
    const int row = blockIdx.x;
    const float* src = (row < B_ROWS) ? emb_i : emb_j;
    const int r = (row < B_ROWS) ? row : (row - B_ROWS);
    const float4* p = (const float4*)(src + (size_t)r * D_DIM);
    const int t = threadIdx.x;              // 256 threads, D/4 = 256 float4
    float4 v = p[t];
    float s = v.x * v.x + v.y * v.y + v.z * v.z + v.w * v.w;
    #pragma unroll
    for (int off = 32; off > 0; off >>= 1) s += __shfl_down(s, off, 64);
    __shared__ float ls[4];
    if ((t & 63) == 0) ls[t >> 6] = s;
    __syncthreads();
    if (t == 0) {
        float tot = ls[0] + ls[1] + ls[2] + ls[3];
        float n = fmaxf(sqrtf(tot), EPSN);
        w[2 + row] = 1.0f / n;
    }
}

// 64x64 output tile per block, 256 threads, 4x4 accumulators per thread.
// sim[a,b] = <emb_j[a,:], emb_i[b,:]> * inv_j[a] * inv_i[b]
// Fused epilogue: off-diag -> log1p(exp(sim-T)); diag -> log1p(exp(T-sim)).
__global__ __launch_bounds__(256) void sim_loss_kernel(
        const float* __restrict__ emb_i,
        const float* __restrict__ emb_j,
        float* __restrict__ w) {
    __shared__ float tJ[64][17];   // pad 17: kills stride-16 bank conflicts
    __shared__ float tI[64][17];
    __shared__ float rn[4], rp[4];

    const int bx = blockIdx.x;     // column tile: z_i rows (index b)
    const int by = blockIdx.y;     // row tile:    z_j rows (index a)
    const int tid = threadIdx.x;
    const int tx = tid & 15;
    const int ty = tid >> 4;

    float acc[4][4] = {{0.f}};

    // staging assignment: 256 threads load 64 rows x 16 cols (one float4 each)
    const int lr = tid >> 2;           // 0..63 row in tile
    const int lc = (tid & 3) << 2;     // 0,4,8,12 col in k-chunk
    const float* baseJ = emb_j + (size_t)(by * 64 + lr) * D_DIM + lc;
    const float* baseI = emb_i + (size_t)(bx * 64 + lr) * D_DIM + lc;

    for (int k0 = 0; k0 < D_DIM; k0 += 16) {
        float4 vj = *(const float4*)(baseJ + k0);
        float4 vi = *(const float4*)(baseI + k0);
        __syncthreads();   // previous iteration's readers done before overwrite
        tJ[lr][lc + 0] = vj.x; tJ[lr][lc + 1] = vj.y;
        tJ[lr][lc + 2] = vj.z; tJ[lr][lc + 3] = vj.w;
        tI[lr][lc + 0] = vi.x; tI[lr][lc + 1] = vi.y;
        tI[lr][lc + 2] = vi.z; tI[lr][lc + 3] = vi.w;
        __syncthreads();
        #pragma unroll
        for (int k = 0; k < 16; ++k) {
            float aj[4], bi[4];
            #pragma unroll
            for (int i = 0; i < 4; ++i) aj[i] = tJ[ty + 16 * i][k];
            #pragma unroll
            for (int j = 0; j < 4; ++j) bi[j] = tI[tx + 16 * j][k];
            #pragma unroll
            for (int i = 0; i < 4; ++i)
                #pragma unroll
                for (int j = 0; j < 4; ++j)
                    acc[i][j] = fmaf(aj[i], bi[j], acc[i][j]);
        }
    }

    // Epilogue: scale by inverse norms, accumulate loss terms.
    float inva[4], invb[4];
    #pragma unroll
    for (int i = 0; i < 4; ++i) inva[i] = w[2 + B_ROWS + (by * 64 + ty + 16 * i)];
    #pragma unroll
    for (int j = 0; j < 4; ++j) invb[j] = w[2 + (bx * 64 + tx + 16 * j)];

    float local_neg = 0.f, local_pos = 0.f;
    #pragma unroll
    for (int i = 0; i < 4; ++i) {
        const int a = by * 64 + ty + 16 * i;
        #pragma unroll
        for (int j = 0; j < 4; ++j) {
            const int b = bx * 64 + tx + 16 * j;
            const float sim = acc[i][j] * inva[i] * invb[j];
            if (a == b) {
                local_pos += log1pf(expf(TEMP - sim));
            } else {
                local_neg += log1pf(expf(sim - TEMP));
            }
        }
    }

    // block reduction, one atomic per block
    #pragma unroll
    for (int off = 32; off > 0; off >>= 1) {
        local_neg += __shfl_down(local_neg, off, 64);
        local_pos += __shfl_down(local_pos, off, 64);
    }
    if ((tid & 63) == 0) { rn[tid >> 6] = local_neg; rp[tid >> 6] = local_pos; }
    __syncthreads();
    if (tid == 0) {
        float tn = rn[0] + rn[1] + rn[2] + rn[3];
        float tp = rp[0] + rp[1] + rp[2] + rp[3];
        atomicAdd(&w[1], tn);
        if (bx == by) atomicAdd(&w[0], tp);   // only diagonal blocks have pos terms
    }
}

__global__ void finalize_kernel(const float* __restrict__ w, float* __restrict__ out) {
    const float pos = w[0] / (float)B_ROWS;
    const float neg = w[1] / ((float)B_ROWS * (float)(B_ROWS - 1));
    out[0] = 0.5f * pos + 0.5f * neg;   // HYPER_GAMMA = 0.5
}

extern "C" void kernel_launch(void* const* d_in, const int* in_sizes, int n_in,
                              void* d_out, int out_size, void* d_ws, size_t ws_size,
                              hipStream_t stream) {
    const float* emb_i = (const float*)d_in[0];
    const float* emb_j = (const float*)d_in[1];
    float* w = (float*)d_ws;
    float* out = (float*)d_out;

    init_acc_kernel<<<1, 1, 0, stream>>>(w);
    row_invnorm_kernel<<<2 * B_ROWS, 256, 0, stream>>>(emb_i, emb_j, w);
    dim3 grid(B_ROWS / 64, B_ROWS / 64);   // 64 x 64 blocks
    sim_loss_kernel<<<grid, 256, 0, stream>>>(emb_i, emb_j, w);
    finalize_kernel<<<1, 1, 0, stream>>>(w, out);
}

// Round 2
// 137.467 us; speedup vs baseline: 5.0520x; 5.0520x over previous
//
#include <hip/hip_runtime.h>
#include <math.h>

#define B_ROWS 4096
#define D_DIM  1024
static constexpr float TEMP = 0.2f;

typedef __attribute__((ext_vector_type(8))) short bf16x8;  // 8 bf16 in 4 VGPRs
typedef __attribute__((ext_vector_type(4))) float f32x4;

// RNE float -> bf16 bits (no NaN handling needed for this data)
__device__ inline unsigned short f2bf(float f) {
    unsigned int u = __float_as_uint(f);
    u += 0x7fffu + ((u >> 16) & 1u);
    return (unsigned short)(u >> 16);
}

// async global->LDS, 16 B per lane, LDS dest = wave-uniform base + lane*16
__device__ inline void gload_lds16(const unsigned short* g, unsigned short* l) {
    __builtin_amdgcn_global_load_lds(
        (const __attribute__((address_space(1))) unsigned int*)g,
        (__attribute__((address_space(3))) unsigned int*)l,
        16, 0, 0);
}

// ws layout: w[0]=pos acc, w[1]=neg acc, then Zi (4096x1024 bf16), Zj (same)

__global__ void init_acc_kernel(float* __restrict__ w) {
    w[0] = 0.0f;
    w[1] = 0.0f;
}

// One block per row; rows [0,B) -> emb_i -> Zi, [B,2B) -> emb_j -> Zj.
// Normalize in fp32, cast to bf16.
__global__ __launch_bounds__(256) void norm_cast_kernel(
        const float* __restrict__ emb_i, const float* __restrict__ emb_j,
        unsigned short* __restrict__ Zi, unsigned short* __restrict__ Zj) {
    const int row = blockIdx.x;
    const float* src;
    unsigned short* dst;
    int r;
    if (row < B_ROWS) { src = emb_i; dst = Zi; r = row; }
    else              { src = emb_j; dst = Zj; r = row - B_ROWS; }

    const int t = threadIdx.x;                         // 256 thr, 1024/4 f4
    const float4* p = (const float4*)(src + (size_t)r * D_DIM);
    float4 v = p[t];
    float s = v.x * v.x + v.y * v.y + v.z * v.z + v.w * v.w;
    #pragma unroll
    for (int off = 32; off > 0; off >>= 1) s += __shfl_down(s, off, 64);
    __shared__ float ls[4];
    __shared__ float invn;
    if ((t & 63) == 0) ls[t >> 6] = s;
    __syncthreads();
    if (t == 0) {
        float tot = ls[0] + ls[1] + ls[2] + ls[3];
        invn = 1.0f / fmaxf(sqrtf(tot), 1e-12f);
    }
    __syncthreads();
    const float inv = invn;
    ushort4 o;
    o.x = f2bf(v.x * inv); o.y = f2bf(v.y * inv);
    o.z = f2bf(v.z * inv); o.w = f2bf(v.w * inv);
    ((ushort4*)(dst + (size_t)r * D_DIM))[t] = o;
}

// 128x128 block tile, 4 waves each owning 64x64 (4x4 MFMA 16x16x32 tiles).
// sim[a,b] = <Zj[a,:], Zi[b,:]> (rows already unit). Fused softplus epilogue.
__global__ __launch_bounds__(256) void simloss_mfma_kernel(
        const unsigned short* __restrict__ Zi,
        const unsigned short* __restrict__ Zj,
        float* __restrict__ w) {
    __shared__ __align__(16) unsigned short lA[128 * 32];  // Zj tile (a rows)
    __shared__ __align__(16) unsigned short lB[128 * 32];  // Zi tile (b rows)
    __shared__ float rn[4], rp[4];

    const int tid  = threadIdx.x;
    const int lane = tid & 63;
    const int wave = tid >> 6;
    const int wy = wave >> 1, wx = wave & 1;

    const int rowBase = blockIdx.y * 128;   // a (Zj rows)
    const int colBase = blockIdx.x * 128;   // b (Zi rows)

    // --- staging addressing: 8 chunks of 1 KB per tile; wave w owns 2w,2w+1
    const int c0 = 2 * wave, c1 = c0 + 1;
    const int srow  = lane >> 2;            // 0..15 row within chunk
    const int skoff = (lane & 3) * 8;       // k-element offset (8 bf16 = 16 B)
    const unsigned short* gA0 = Zj + (size_t)(rowBase + 16 * c0 + srow) * D_DIM + skoff;
    const unsigned short* gA1 = Zj + (size_t)(rowBase + 16 * c1 + srow) * D_DIM + skoff;
    const unsigned short* gB0 = Zi + (size_t)(colBase + 16 * c0 + srow) * D_DIM + skoff;
    const unsigned short* gB1 = Zi + (size_t)(colBase + 16 * c1 + srow) * D_DIM + skoff;
    unsigned short* sA0 = lA + c0 * 512;    // 512 shorts = 1 KB chunk
    unsigned short* sA1 = lA + c1 * 512;
    unsigned short* sB0 = lB + c0 * 512;
    unsigned short* sB1 = lB + c1 * 512;

    // --- fragment read base: row (lane&15) of wave's sub-tile, k quad*8
    const unsigned short* fA = lA + ((wy * 64 + (lane & 15)) * 32 + (lane >> 4) * 8);
    const unsigned short* fB = lB + ((wx * 64 + (lane & 15)) * 32 + (lane >> 4) * 8);

    f32x4 acc[4][4];
    #pragma unroll
    for (int i = 0; i < 4; ++i)
        #pragma unroll
        for (int j = 0; j < 4; ++j)
            acc[i][j] = (f32x4){0.f, 0.f, 0.f, 0.f};

    for (int k0 = 0; k0 < D_DIM; k0 += 32) {
        __syncthreads();                    // prior readers done
        gload_lds16(gA0, sA0);
        gload_lds16(gA1, sA1);
        gload_lds16(gB0, sB0);
        gload_lds16(gB1, sB1);
        gA0 += 32; gA1 += 32; gB0 += 32; gB1 += 32;
        __syncthreads();                    // compiler drains vmcnt here

        bf16x8 af[4], bf[4];
        #pragma unroll
        for (int i = 0; i < 4; ++i) af[i] = *(const bf16x8*)(fA + i * 16 * 32);
        #pragma unroll
        for (int j = 0; j < 4; ++j) bf[j] = *(const bf16x8*)(fB + j * 16 * 32);
        #pragma unroll
        for (int i = 0; i < 4; ++i)
            #pragma unroll
            for (int j = 0; j < 4; ++j)
                acc[i][j] = __builtin_amdgcn_mfma_f32_16x16x32_bf16(
                    af[i], bf[j], acc[i][j], 0, 0, 0);
    }

    // --- fused epilogue: softplus terms; C layout row=(lane>>4)*4+r, col=lane&15
    const int cr = (lane >> 4) * 4;
    const int cc = lane & 15;
    float neg = 0.f, pos = 0.f;
    #pragma unroll
    for (int i = 0; i < 4; ++i) {
        const int abase = rowBase + wy * 64 + i * 16 + cr;
        #pragma unroll
        for (int j = 0; j < 4; ++j) {
            const int b = colBase + wx * 64 + j * 16 + cc;
            #pragma unroll
            for (int r = 0; r < 4; ++r) {
                const float x = acc[i][j][r] - TEMP;   // sim - T
                if (abase + r == b) pos += __logf(1.0f + __expf(-x));
                else                neg += __logf(1.0f + __expf(x));
            }
        }
    }

    #pragma unroll
    for (int off = 32; off > 0; off >>= 1) {
        neg += __shfl_down(neg, off, 64);
        pos += __shfl_down(pos, off, 64);
    }
    if (lane == 0) { rn[wave] = neg; rp[wave] = pos; }
    __syncthreads();
    if (tid == 0) {
        atomicAdd(&w[1], rn[0] + rn[1] + rn[2] + rn[3]);
        if (blockIdx.x == blockIdx.y)
            atomicAdd(&w[0], rp[0] + rp[1] + rp[2] + rp[3]);
    }
}

__global__ void finalize_kernel(const float* __restrict__ w, float* __restrict__ out) {
    const float pos = w[0] / (float)B_ROWS;
    const float neg = w[1] / ((float)B_ROWS * (float)(B_ROWS - 1));
    out[0] = 0.5f * pos + 0.5f * neg;   // HYPER_GAMMA = 0.5
}

extern "C" void kernel_launch(void* const* d_in, const int* in_sizes, int n_in,
                              void* d_out, int out_size, void* d_ws, size_t ws_size,
                              hipStream_t stream) {
    const float* emb_i = (const float*)d_in[0];
    const float* emb_j = (const float*)d_in[1];
    float* w = (float*)d_ws;
    unsigned short* Zi = (unsigned short*)(w + 16);
    unsigned short* Zj = Zi + (size_t)B_ROWS * D_DIM;
    float* out = (float*)d_out;

    init_acc_kernel<<<1, 1, 0, stream>>>(w);
    norm_cast_kernel<<<2 * B_ROWS, 256, 0, stream>>>(emb_i, emb_j, Zi, Zj);
    dim3 grid(B_ROWS / 128, B_ROWS / 128);   // 32 x 32 tiles
    simloss_mfma_kernel<<<grid, 256, 0, stream>>>(Zi, Zj, w);
    finalize_kernel<<<1, 1, 0, stream>>>(w, out);
}